// Round 1
// baseline (110.797 us; speedup 1.0000x reference)
//
#include <hip/hip_runtime.h>
#include <hip/hip_bf16.h>
#include <math.h>

#define B_   2
#define T_   4096
#define E_   256
#define H_   4
#define HD_  64
#define W_   65
#define PADW 32
#define M_   (B_*T_)
#define K_   E_

// -------------------- Kernel 1: QKV projection GEMM --------------------
// qkv[m][n] = sum_k x[m][k]*Wqkv[n][k] + bqkv[n]; split/scatter to q,k,v
// in [B*H][T][HD] layout; q scaled by HD^-0.5 = 0.125.
__global__ __launch_bounds__(256) void qkv_kernel(
    const float* __restrict__ x, const float* __restrict__ Wqkv,
    const float* __restrict__ bqkv,
    float* __restrict__ q, float* __restrict__ k, float* __restrict__ v)
{
    __shared__ float As[64*64];
    __shared__ float Bs[64*64];
    const int tid = threadIdx.x;
    const int m0 = blockIdx.y * 64;
    const int n0 = blockIdx.x * 64;
    const int ty = tid >> 4, tx = tid & 15;

    float acc[4][4] = {};

    for (int k0 = 0; k0 < K_; k0 += 64) {
        #pragma unroll
        for (int l = 0; l < 4; ++l) {
            int idx = tid + l*256;          // 0..1023
            int row = idx >> 4;             // 0..63
            int c4  = (idx & 15) << 2;      // 0..60
            int sc  = c4 ^ (((row >> 2) & 7) << 2);   // XOR swizzle (16B granule)
            float4 av = *reinterpret_cast<const float4*>(x + (size_t)(m0+row)*K_ + k0 + c4);
            *reinterpret_cast<float4*>(&As[row*64 + sc]) = av;
            float4 bv = *reinterpret_cast<const float4*>(Wqkv + (size_t)(n0+row)*K_ + k0 + c4);
            *reinterpret_cast<float4*>(&Bs[row*64 + sc]) = bv;
        }
        __syncthreads();
        #pragma unroll 4
        for (int kk = 0; kk < 64; kk += 4) {
            float4 a[4], b[4];
            #pragma unroll
            for (int i = 0; i < 4; ++i) {
                int r = ty*4 + i;
                a[i] = *reinterpret_cast<const float4*>(&As[r*64 + (kk ^ (((r >> 2) & 7) << 2))]);
            }
            #pragma unroll
            for (int j = 0; j < 4; ++j) {
                int r = tx*4 + j;
                b[j] = *reinterpret_cast<const float4*>(&Bs[r*64 + (kk ^ (((r >> 2) & 7) << 2))]);
            }
            #pragma unroll
            for (int i = 0; i < 4; ++i)
                #pragma unroll
                for (int j = 0; j < 4; ++j)
                    acc[i][j] += a[i].x*b[j].x + a[i].y*b[j].y + a[i].z*b[j].z + a[i].w*b[j].w;
        }
        __syncthreads();
    }

    // Epilogue: n0 is a multiple of 64 so the whole tile targets one of q/k/v
    // and one head; d = n&63 is 4-consecutive -> float4 stores.
    const int nbase = n0 + tx*4;
    const int which = n0 >> 8;          // 0=q, 1=k, 2=v (uniform per block)
    const int e0 = nbase & 255;
    const int h  = e0 >> 6;
    const int d0 = e0 & 63;
    float bias[4];
    #pragma unroll
    for (int j = 0; j < 4; ++j) bias[j] = bqkv[nbase + j];
    float* dst = (which == 0) ? q : (which == 1) ? k : v;
    const float scale = (which == 0) ? 0.125f : 1.0f;
    #pragma unroll
    for (int i = 0; i < 4; ++i) {
        int m  = m0 + ty*4 + i;
        int bb = m >> 12;               // m / T_
        int t  = m & (T_-1);
        float4 o;
        o.x = (acc[i][0] + bias[0]) * scale;
        o.y = (acc[i][1] + bias[1]) * scale;
        o.z = (acc[i][2] + bias[2]) * scale;
        o.w = (acc[i][3] + bias[3]) * scale;
        *reinterpret_cast<float4*>(dst + ((size_t)(bb*H_ + h)*T_ + t)*HD_ + d0) = o;
    }
}

// -------------------- Kernel 2: sliding-window attention --------------------
// Per block: one (b,h), 32 query rows. Stage 96 K/V rows (window span) in LDS.
// OOB rows stored as zeros -> score 0, matching jnp.pad + softmax semantics.
__global__ __launch_bounds__(256) void attn_kernel(
    const float* __restrict__ q, const float* __restrict__ k,
    const float* __restrict__ v, float* __restrict__ ao)
{
    __shared__ float ks[96*64];
    __shared__ float vs[96*64];
    __shared__ float ps[32*66];
    const int tid = threadIdx.x;
    const int bh = blockIdx.y;
    const int t0 = blockIdx.x * 32;
    const float* kb = k + (size_t)bh*T_*HD_;
    const float* vb = v + (size_t)bh*T_*HD_;
    const float* qb = q + (size_t)bh*T_*HD_;

    #pragma unroll
    for (int l = 0; l < 6; ++l) {
        int idx = tid + l*256;          // 0..1535 (96 rows x 16 float4)
        int row = idx >> 4;
        int c4  = (idx & 15) << 2;
        int g   = t0 - PADW + row;
        float4 kv = make_float4(0.f,0.f,0.f,0.f);
        float4 vv = kv;
        if ((unsigned)g < (unsigned)T_) {
            kv = *reinterpret_cast<const float4*>(kb + (size_t)g*HD_ + c4);
            vv = *reinterpret_cast<const float4*>(vb + (size_t)g*HD_ + c4);
        }
        int sc = c4 ^ ((row & 7) << 2);  // XOR swizzle by row
        *reinterpret_cast<float4*>(&ks[row*64 + sc]) = kv;
        *reinterpret_cast<float4*>(&vs[row*64 + sc]) = vv;
    }
    __syncthreads();

    const int row = tid >> 3;           // 0..31
    const int c   = tid & 7;            // 0..7

    // q row into registers (global, L1/L2-cached; 8-way duplicate per row)
    float qr[64];
    const float* qrow = qb + (size_t)(t0 + row)*HD_;
    #pragma unroll
    for (int i = 0; i < 16; ++i) {
        float4 t4 = *reinterpret_cast<const float4*>(qrow + i*4);
        qr[i*4+0]=t4.x; qr[i*4+1]=t4.y; qr[i*4+2]=t4.z; qr[i*4+3]=t4.w;
    }

    // scores (each of 8 lanes per row handles w = c, c+8, ...)
    float mx = -3.4e38f;
    for (int w = c; w < W_; w += 8) {
        int r = row + w;
        float s = 0.f;
        #pragma unroll
        for (int i = 0; i < 16; ++i) {
            float4 k4 = *reinterpret_cast<const float4*>(&ks[r*64 + ((i*4) ^ ((r & 7) << 2))]);
            s += qr[i*4]*k4.x + qr[i*4+1]*k4.y + qr[i*4+2]*k4.z + qr[i*4+3]*k4.w;
        }
        ps[row*66 + w] = s;
        mx = fmaxf(mx, s);
    }
    mx = fmaxf(mx, __shfl_xor(mx, 1));
    mx = fmaxf(mx, __shfl_xor(mx, 2));
    mx = fmaxf(mx, __shfl_xor(mx, 4));
    float sum = 0.f;
    for (int w = c; w < W_; w += 8) {
        float e = __expf(ps[row*66 + w] - mx);
        ps[row*66 + w] = e;
        sum += e;
    }
    sum += __shfl_xor(sum, 1);
    sum += __shfl_xor(sum, 2);
    sum += __shfl_xor(sum, 4);
    const float inv = 1.f / sum;
    __syncthreads();

    // PV: lane owns 8 of 64 output dims for its row
    float o[8] = {};
    for (int w = 0; w < W_; ++w) {
        int r = row + w;
        float pw = ps[row*66 + w];
        #pragma unroll
        for (int i = 0; i < 2; ++i) {
            int col = c*8 + i*4;
            float4 v4 = *reinterpret_cast<const float4*>(&vs[r*64 + (col ^ ((r & 7) << 2))]);
            o[i*4+0] += pw*v4.x; o[i*4+1] += pw*v4.y;
            o[i*4+2] += pw*v4.z; o[i*4+3] += pw*v4.w;
        }
    }
    const int bb = bh >> 2, hh = bh & 3;
    float* op = ao + ((size_t)bb*T_ + (t0 + row))*E_ + hh*HD_ + c*8;
    *reinterpret_cast<float4*>(op)     = make_float4(o[0]*inv, o[1]*inv, o[2]*inv, o[3]*inv);
    *reinterpret_cast<float4*>(op + 4) = make_float4(o[4]*inv, o[5]*inv, o[6]*inv, o[7]*inv);
}

// -------------------- Kernel 3: output projection GEMM --------------------
__global__ __launch_bounds__(256) void proj_kernel(
    const float* __restrict__ ao, const float* __restrict__ Wout,
    const float* __restrict__ bout, float* __restrict__ out)
{
    __shared__ float As[64*64];
    __shared__ float Bs[64*64];
    const int tid = threadIdx.x;
    const int m0 = blockIdx.y * 64;
    const int n0 = blockIdx.x * 64;
    const int ty = tid >> 4, tx = tid & 15;

    float acc[4][4] = {};

    for (int k0 = 0; k0 < K_; k0 += 64) {
        #pragma unroll
        for (int l = 0; l < 4; ++l) {
            int idx = tid + l*256;
            int row = idx >> 4;
            int c4  = (idx & 15) << 2;
            int sc  = c4 ^ (((row >> 2) & 7) << 2);
            float4 av = *reinterpret_cast<const float4*>(ao + (size_t)(m0+row)*K_ + k0 + c4);
            *reinterpret_cast<float4*>(&As[row*64 + sc]) = av;
            float4 bv = *reinterpret_cast<const float4*>(Wout + (size_t)(n0+row)*K_ + k0 + c4);
            *reinterpret_cast<float4*>(&Bs[row*64 + sc]) = bv;
        }
        __syncthreads();
        #pragma unroll 4
        for (int kk = 0; kk < 64; kk += 4) {
            float4 a[4], b[4];
            #pragma unroll
            for (int i = 0; i < 4; ++i) {
                int r = ty*4 + i;
                a[i] = *reinterpret_cast<const float4*>(&As[r*64 + (kk ^ (((r >> 2) & 7) << 2))]);
            }
            #pragma unroll
            for (int j = 0; j < 4; ++j) {
                int r = tx*4 + j;
                b[j] = *reinterpret_cast<const float4*>(&Bs[r*64 + (kk ^ (((r >> 2) & 7) << 2))]);
            }
            #pragma unroll
            for (int i = 0; i < 4; ++i)
                #pragma unroll
                for (int j = 0; j < 4; ++j)
                    acc[i][j] += a[i].x*b[j].x + a[i].y*b[j].y + a[i].z*b[j].z + a[i].w*b[j].w;
        }
        __syncthreads();
    }

    const int nbase = n0 + tx*4;
    float bias[4];
    #pragma unroll
    for (int j = 0; j < 4; ++j) bias[j] = bout[nbase + j];
    #pragma unroll
    for (int i = 0; i < 4; ++i) {
        int m = m0 + ty*4 + i;
        float4 o;
        o.x = acc[i][0] + bias[0];
        o.y = acc[i][1] + bias[1];
        o.z = acc[i][2] + bias[2];
        o.w = acc[i][3] + bias[3];
        *reinterpret_cast<float4*>(out + (size_t)m*E_ + nbase) = o;
    }
}

extern "C" void kernel_launch(void* const* d_in, const int* in_sizes, int n_in,
                              void* d_out, int out_size, void* d_ws, size_t ws_size,
                              hipStream_t stream) {
    const float* x    = (const float*)d_in[0];
    const float* Wqkv = (const float*)d_in[1];
    const float* bqkv = (const float*)d_in[2];
    const float* Wout = (const float*)d_in[3];
    const float* bout = (const float*)d_in[4];
    float* out = (float*)d_out;

    // workspace: q, k, v in [B*H][T][HD], attn_out in [B][T][E]; 33.5 MB fp32
    float* ws = (float*)d_ws;
    const size_t SZ = (size_t)B_ * H_ * T_ * HD_;   // 2,097,152
    float* q  = ws;
    float* k  = ws + SZ;
    float* v  = ws + 2*SZ;
    float* ao = ws + 3*SZ;

    qkv_kernel<<<dim3(12, 128), 256, 0, stream>>>(x, Wqkv, bqkv, q, k, v);
    attn_kernel<<<dim3(128, 8), 256, 0, stream>>>(q, k, v, ao);
    proj_kernel<<<dim3(4, 128), 256, 0, stream>>>(ao, Wout, bout, out);
}

// Round 2
// 48.745 us; speedup vs baseline: 2.2730x; 2.2730x over previous
//
#include <hip/hip_runtime.h>
#include <hip/hip_bf16.h>
#include <math.h>

#define T_   4096
#define E_   256
#define H_   4
#define HD_  64

typedef __attribute__((ext_vector_type(8))) short short8;
typedef __attribute__((ext_vector_type(4))) float f32x4;
typedef unsigned int u32;
typedef unsigned short ushort_t;

typedef const __attribute__((address_space(1))) u32* gas_ptr;
typedef __attribute__((address_space(3))) u32* las_ptr;

__device__ __forceinline__ void gld_lds16(const void* g, void* l) {
    // async global->LDS, 16B per lane; LDS dest = wave-uniform base + lane*16
    __builtin_amdgcn_global_load_lds((gas_ptr)g, (las_ptr)l, 16, 0, 0);
}

__device__ __forceinline__ float bf_lo(u32 w) { return __uint_as_float(w << 16); }
__device__ __forceinline__ float bf_hi(u32 w) { return __uint_as_float(w & 0xffff0000u); }
__device__ __forceinline__ ushort_t f2bf(float f) {
    __hip_bfloat16 h = __float2bfloat16(f);
    return *reinterpret_cast<ushort_t*>(&h);
}

// -------------------- Kernel 0: fp32 -> bf16 convert (x, Wqkv, Wout) ----------
__global__ __launch_bounds__(256) void cvt_kernel(
    const float* __restrict__ x, const float* __restrict__ wq,
    const float* __restrict__ wo,
    ushort_t* __restrict__ xb, ushort_t* __restrict__ wqb, ushort_t* __restrict__ wob)
{
    int idx = blockIdx.x * 256 + threadIdx.x;   // unit of 8 elems
    const float* src; ushort_t* dst; int off;
    if (idx < 262144)       { src = x;  dst = xb;  off = idx * 8; }
    else if (idx < 286720)  { src = wq; dst = wqb; off = (idx - 262144) * 8; }
    else                    { src = wo; dst = wob; off = (idx - 286720) * 8; }
    float4 a = *(const float4*)(src + off);
    float4 b = *(const float4*)(src + off + 4);
    short8 p;
    p[0] = (short)f2bf(a.x); p[1] = (short)f2bf(a.y);
    p[2] = (short)f2bf(a.z); p[3] = (short)f2bf(a.w);
    p[4] = (short)f2bf(b.x); p[5] = (short)f2bf(b.y);
    p[6] = (short)f2bf(b.z); p[7] = (short)f2bf(b.w);
    *(short8*)(dst + off) = p;
}

// -------------------- MFMA GEMM: C[M x 64tile] = A[M][256] * B[N][256]^T -----
// MODE 0: qkv epilogue (bf16 q/k/v scatter, q*0.125). MODE 1: fp32 out + bias.
// Block: 256 thr (4 waves), tile 128(M) x 64(N), BK=64, double-buffered LDS.
template<int MODE>
__global__ __launch_bounds__(256) void gemm_kernel(
    const char* __restrict__ A, const char* __restrict__ Bw,
    const float* __restrict__ bias,
    ushort_t* __restrict__ o0, ushort_t* __restrict__ o1, ushort_t* __restrict__ o2,
    float* __restrict__ of)
{
    __shared__ __align__(16) char As[2][16384];   // [128][64] bf16, swizzled
    __shared__ __align__(16) char Bs[2][8192];    // [64][64]  bf16, swizzled
    const int tid  = threadIdx.x;
    const int lane = tid & 63;
    const int wid  = tid >> 6;
    const int m0   = blockIdx.y * 128;
    const int bx   = blockIdx.x;
    const int n0   = bx * 64;

    f32x4 acc[2][4];
    #pragma unroll
    for (int i = 0; i < 2; ++i)
        #pragma unroll
        for (int j = 0; j < 4; ++j)
            acc[i][j] = (f32x4){0.f, 0.f, 0.f, 0.f};

    auto stage = [&](int buf, int ks) {
        const int kb = ks * 128;                  // byte offset within 512B row
        #pragma unroll
        for (int i = 0; i < 4; ++i) {             // A: 16KB = 16 x 1KB units
            int u   = wid * 4 + i;
            int o   = u * 1024 + lane * 16;
            int row = o >> 7;
            int cb  = o & 127;
            int sc  = cb ^ ((row & 7) << 4);      // pre-swizzled global source
            gld_lds16(A + (size_t)(m0 + row) * 512 + kb + sc, &As[buf][u * 1024]);
        }
        #pragma unroll
        for (int i = 0; i < 2; ++i) {             // B: 8KB = 8 x 1KB units
            int u   = wid * 2 + i;
            int o   = u * 1024 + lane * 16;
            int row = o >> 7;
            int cb  = o & 127;
            int sc  = cb ^ ((row & 7) << 4);
            gld_lds16(Bw + (size_t)(n0 + row) * 512 + kb + sc, &Bs[buf][u * 1024]);
        }
    };

    auto compute = [&](int buf) {
        #pragma unroll
        for (int k2 = 0; k2 < 2; ++k2) {
            short8 af[2], bfr[4];
            #pragma unroll
            for (int mf = 0; mf < 2; ++mf) {
                int row = wid * 32 + mf * 16 + (lane & 15);
                int off = (k2 * 64 + (lane >> 4) * 16) ^ ((row & 7) << 4);
                af[mf] = *(const short8*)(&As[buf][row * 128 + off]);
            }
            #pragma unroll
            for (int nf = 0; nf < 4; ++nf) {
                int row = nf * 16 + (lane & 15);
                int off = (k2 * 64 + (lane >> 4) * 16) ^ ((row & 7) << 4);
                bfr[nf] = *(const short8*)(&Bs[buf][row * 128 + off]);
            }
            #pragma unroll
            for (int mf = 0; mf < 2; ++mf)
                #pragma unroll
                for (int nf = 0; nf < 4; ++nf)
                    acc[mf][nf] = __builtin_amdgcn_mfma_f32_16x16x32_bf16(
                        af[mf], bfr[nf], acc[mf][nf], 0, 0, 0);
        }
    };

    stage(0, 0);
    __syncthreads();
    #pragma unroll
    for (int t = 0; t < 4; ++t) {
        if (t < 3) stage((t + 1) & 1, t + 1);
        compute(t & 1);
        __syncthreads();
    }

    if (MODE == 0) {
        const int which = bx >> 2;                 // 0=q 1=k 2=v (uniform)
        const int h     = bx & 3;
        ushort_t* dst = (which == 0) ? o0 : (which == 1) ? o1 : o2;
        const float scale = (which == 0) ? 0.125f : 1.0f;
        #pragma unroll
        for (int nf = 0; nf < 4; ++nf) {
            int d = nf * 16 + (lane & 15);
            float bv = bias[n0 + d];
            #pragma unroll
            for (int mf = 0; mf < 2; ++mf)
                #pragma unroll
                for (int r = 0; r < 4; ++r) {
                    int m  = m0 + wid * 32 + mf * 16 + (lane >> 4) * 4 + r;
                    int bb = m >> 12;
                    int t  = m & (T_ - 1);
                    float v = (acc[mf][nf][r] + bv) * scale;
                    dst[((size_t)(bb * H_ + h) * T_ + t) * HD_ + d] = f2bf(v);
                }
        }
    } else {
        #pragma unroll
        for (int nf = 0; nf < 4; ++nf) {
            int n = n0 + nf * 16 + (lane & 15);
            float bv = bias[n];
            #pragma unroll
            for (int mf = 0; mf < 2; ++mf)
                #pragma unroll
                for (int r = 0; r < 4; ++r) {
                    int m = m0 + wid * 32 + mf * 16 + (lane >> 4) * 4 + r;
                    of[(size_t)m * E_ + n] = acc[mf][nf][r] + bv;
                }
        }
    }
}

// -------------------- Kernel 2: sliding-window attention (bf16 in/out) -------
__global__ __launch_bounds__(256) void attn_kernel(
    const ushort_t* __restrict__ q, const ushort_t* __restrict__ k,
    const ushort_t* __restrict__ v, ushort_t* __restrict__ ao)
{
    __shared__ __align__(16) char ks[96 * 128];   // [96][64] bf16, swizzled
    __shared__ __align__(16) char vs[96 * 128];
    __shared__ float ps[32 * 66];
    const int tid = threadIdx.x;
    const int bh  = blockIdx.y;
    const int t0  = blockIdx.x * 32;
    const char* kb = (const char*)(k + (size_t)bh * T_ * HD_);
    const char* vb = (const char*)(v + (size_t)bh * T_ * HD_);
    const char* qb = (const char*)(q + (size_t)bh * T_ * HD_);

    #pragma unroll
    for (int l = 0; l < 3; ++l) {
        int u   = tid + l * 256;                  // 0..767 (96 rows x 8 units)
        int row = u >> 3;
        int cb  = (u & 7) * 16;
        int g   = t0 - 32 + row;
        int4 kv = make_int4(0, 0, 0, 0), vv = make_int4(0, 0, 0, 0);
        if ((unsigned)g < (unsigned)T_) {
            kv = *(const int4*)(kb + (size_t)g * 128 + cb);
            vv = *(const int4*)(vb + (size_t)g * 128 + cb);
        }
        int sc = cb ^ ((row & 7) << 4);
        *(int4*)(&ks[row * 128 + sc]) = kv;
        *(int4*)(&vs[row * 128 + sc]) = vv;
    }
    __syncthreads();

    const int row = tid >> 3;                     // 0..31
    const int c   = tid & 7;                      // 0..7

    float qr[64];
    {
        const char* qrow = qb + (size_t)(t0 + row) * 128;
        #pragma unroll
        for (int i = 0; i < 8; ++i) {
            int4 t4 = *(const int4*)(qrow + i * 16);
            u32* w = (u32*)&t4;
            #pragma unroll
            for (int j = 0; j < 4; ++j) {
                qr[i * 8 + 2 * j]     = bf_lo(w[j]);
                qr[i * 8 + 2 * j + 1] = bf_hi(w[j]);
            }
        }
    }

    float mx = -3.4e38f;
    #pragma unroll
    for (int wi = 0; wi < 9; ++wi) {
        int w = c + wi * 8;
        if (w < 65) {
            int r = row + w;
            float s = 0.f;
            #pragma unroll
            for (int i = 0; i < 8; ++i) {
                int4 k4 = *(const int4*)(&ks[r * 128 + ((i * 16) ^ ((r & 7) << 4))]);
                u32* uu = (u32*)&k4;
                #pragma unroll
                for (int j = 0; j < 4; ++j)
                    s += bf_lo(uu[j]) * qr[i * 8 + 2 * j]
                       + bf_hi(uu[j]) * qr[i * 8 + 2 * j + 1];
            }
            ps[row * 66 + w] = s;
            mx = fmaxf(mx, s);
        }
    }
    mx = fmaxf(mx, __shfl_xor(mx, 1));
    mx = fmaxf(mx, __shfl_xor(mx, 2));
    mx = fmaxf(mx, __shfl_xor(mx, 4));
    float sum = 0.f;
    #pragma unroll
    for (int wi = 0; wi < 9; ++wi) {
        int w = c + wi * 8;
        if (w < 65) {
            float e = __expf(ps[row * 66 + w] - mx);
            ps[row * 66 + w] = e;
            sum += e;
        }
    }
    sum += __shfl_xor(sum, 1);
    sum += __shfl_xor(sum, 2);
    sum += __shfl_xor(sum, 4);
    const float inv = 1.f / sum;

    float o[8] = {};
    for (int w = 0; w < 65; ++w) {
        int r = row + w;
        float pw = ps[row * 66 + w];
        int4 v4 = *(const int4*)(&vs[r * 128 + ((c * 16) ^ ((r & 7) << 4))]);
        u32* uu = (u32*)&v4;
        #pragma unroll
        for (int j = 0; j < 4; ++j) {
            o[2 * j]     += pw * bf_lo(uu[j]);
            o[2 * j + 1] += pw * bf_hi(uu[j]);
        }
    }
    const int bb = bh >> 2, hh = bh & 3;
    short8 pk;
    #pragma unroll
    for (int j = 0; j < 8; ++j) pk[j] = (short)f2bf(o[j] * inv);
    *(short8*)(&ao[((size_t)bb * T_ + (t0 + row)) * E_ + hh * HD_ + c * 8]) = pk;
}

extern "C" void kernel_launch(void* const* d_in, const int* in_sizes, int n_in,
                              void* d_out, int out_size, void* d_ws, size_t ws_size,
                              hipStream_t stream) {
    const float* x    = (const float*)d_in[0];
    const float* Wqkv = (const float*)d_in[1];
    const float* bqkv = (const float*)d_in[2];
    const float* Wout = (const float*)d_in[3];
    const float* bout = (const float*)d_in[4];
    float* out = (float*)d_out;

    char* ws = (char*)d_ws;
    ushort_t* xb  = (ushort_t*)(ws);                 // 4 MB  (8192x256)
    ushort_t* wqb = (ushort_t*)(ws + 4194304);       // 384 KB (768x256)
    ushort_t* wob = (ushort_t*)(ws + 4587520);       // 128 KB (256x256)
    ushort_t* qb  = (ushort_t*)(ws + 4718592);       // 4 MB  [BH][T][64]
    ushort_t* kbp = (ushort_t*)(ws + 8912896);       // 4 MB
    ushort_t* vbp = (ushort_t*)(ws + 13107200);      // 4 MB
    ushort_t* aob = (ushort_t*)(ws + 17301504);      // 4 MB  [B][T][256]

    cvt_kernel<<<1152, 256, 0, stream>>>(x, Wqkv, Wout, xb, wqb, wob);
    gemm_kernel<0><<<dim3(12, 64), 256, 0, stream>>>(
        (const char*)xb, (const char*)wqb, bqkv, qb, kbp, vbp, nullptr);
    attn_kernel<<<dim3(128, 8), 256, 0, stream>>>(qb, kbp, vbp, aob);
    gemm_kernel<1><<<dim3(4, 64), 256, 0, stream>>>(
        (const char*)aob, (const char*)wob, bout, nullptr, nullptr, nullptr, out);
}

// Round 3
// 34.460 us; speedup vs baseline: 3.2152x; 1.4145x over previous
//
#include <hip/hip_runtime.h>
#include <hip/hip_bf16.h>
#include <math.h>

#define T_   4096
#define E_   256
#define H_   4
#define HD_  64

typedef __attribute__((ext_vector_type(8))) short short8;
typedef __attribute__((ext_vector_type(4))) float f32x4;
typedef unsigned int u32;
typedef unsigned short ushort_t;

typedef const __attribute__((address_space(1))) u32* gas_ptr;
typedef __attribute__((address_space(3))) u32* las_ptr;

__device__ __forceinline__ void gld_lds16(const void* g, void* l) {
    __builtin_amdgcn_global_load_lds((gas_ptr)g, (las_ptr)l, 16, 0, 0);
}

__device__ __forceinline__ float bf_lo(u32 w) { return __uint_as_float(w << 16); }
__device__ __forceinline__ float bf_hi(u32 w) { return __uint_as_float(w & 0xffff0000u); }
__device__ __forceinline__ ushort_t f2bf(float f) {
    __hip_bfloat16 h = __float2bfloat16(f);
    return *reinterpret_cast<ushort_t*>(&h);
}

// -------------------- Kernel 0: fp32 -> bf16 convert (x, Wqkv, Wout) ----------
__global__ __launch_bounds__(256) void cvt_kernel(
    const float* __restrict__ x, const float* __restrict__ wq,
    const float* __restrict__ wo,
    ushort_t* __restrict__ xb, ushort_t* __restrict__ wqb, ushort_t* __restrict__ wob)
{
    int idx = blockIdx.x * 256 + threadIdx.x;   // unit of 8 elems
    const float* src; ushort_t* dst; int off;
    if (idx < 262144)       { src = x;  dst = xb;  off = idx * 8; }
    else if (idx < 286720)  { src = wq; dst = wqb; off = (idx - 262144) * 8; }
    else                    { src = wo; dst = wob; off = (idx - 286720) * 8; }
    float4 a = *(const float4*)(src + off);
    float4 b = *(const float4*)(src + off + 4);
    short8 p;
    p[0] = (short)f2bf(a.x); p[1] = (short)f2bf(a.y);
    p[2] = (short)f2bf(a.z); p[3] = (short)f2bf(a.w);
    p[4] = (short)f2bf(b.x); p[5] = (short)f2bf(b.y);
    p[6] = (short)f2bf(b.z); p[7] = (short)f2bf(b.w);
    *(short8*)(dst + off) = p;
}

// -------------------- MFMA GEMM (unchanged from round 2) --------------------
template<int MODE>
__global__ __launch_bounds__(256) void gemm_kernel(
    const char* __restrict__ A, const char* __restrict__ Bw,
    const float* __restrict__ bias,
    ushort_t* __restrict__ o0, ushort_t* __restrict__ o1, ushort_t* __restrict__ o2,
    float* __restrict__ of)
{
    __shared__ __align__(16) char As[2][16384];   // [128][64] bf16, swizzled
    __shared__ __align__(16) char Bs[2][8192];    // [64][64]  bf16, swizzled
    const int tid  = threadIdx.x;
    const int lane = tid & 63;
    const int wid  = tid >> 6;
    const int m0   = blockIdx.y * 128;
    const int bx   = blockIdx.x;
    const int n0   = bx * 64;

    f32x4 acc[2][4];
    #pragma unroll
    for (int i = 0; i < 2; ++i)
        #pragma unroll
        for (int j = 0; j < 4; ++j)
            acc[i][j] = (f32x4){0.f, 0.f, 0.f, 0.f};

    auto stage = [&](int buf, int ks) {
        const int kb = ks * 128;
        #pragma unroll
        for (int i = 0; i < 4; ++i) {
            int u   = wid * 4 + i;
            int o   = u * 1024 + lane * 16;
            int row = o >> 7;
            int cb  = o & 127;
            int sc  = cb ^ ((row & 7) << 4);
            gld_lds16(A + (size_t)(m0 + row) * 512 + kb + sc, &As[buf][u * 1024]);
        }
        #pragma unroll
        for (int i = 0; i < 2; ++i) {
            int u   = wid * 2 + i;
            int o   = u * 1024 + lane * 16;
            int row = o >> 7;
            int cb  = o & 127;
            int sc  = cb ^ ((row & 7) << 4);
            gld_lds16(Bw + (size_t)(n0 + row) * 512 + kb + sc, &Bs[buf][u * 1024]);
        }
    };

    auto compute = [&](int buf) {
        #pragma unroll
        for (int k2 = 0; k2 < 2; ++k2) {
            short8 af[2], bfr[4];
            #pragma unroll
            for (int mf = 0; mf < 2; ++mf) {
                int row = wid * 32 + mf * 16 + (lane & 15);
                int off = (k2 * 64 + (lane >> 4) * 16) ^ ((row & 7) << 4);
                af[mf] = *(const short8*)(&As[buf][row * 128 + off]);
            }
            #pragma unroll
            for (int nf = 0; nf < 4; ++nf) {
                int row = nf * 16 + (lane & 15);
                int off = (k2 * 64 + (lane >> 4) * 16) ^ ((row & 7) << 4);
                bfr[nf] = *(const short8*)(&Bs[buf][row * 128 + off]);
            }
            #pragma unroll
            for (int mf = 0; mf < 2; ++mf)
                #pragma unroll
                for (int nf = 0; nf < 4; ++nf)
                    acc[mf][nf] = __builtin_amdgcn_mfma_f32_16x16x32_bf16(
                        af[mf], bfr[nf], acc[mf][nf], 0, 0, 0);
        }
    };

    stage(0, 0);
    __syncthreads();
    #pragma unroll
    for (int t = 0; t < 4; ++t) {
        if (t < 3) stage((t + 1) & 1, t + 1);
        compute(t & 1);
        __syncthreads();
    }

    if (MODE == 0) {
        const int which = bx >> 2;
        const int h     = bx & 3;
        ushort_t* dst = (which == 0) ? o0 : (which == 1) ? o1 : o2;
        const float scale = (which == 0) ? 0.125f : 1.0f;
        #pragma unroll
        for (int nf = 0; nf < 4; ++nf) {
            int d = nf * 16 + (lane & 15);
            float bv = bias[n0 + d];
            #pragma unroll
            for (int mf = 0; mf < 2; ++mf)
                #pragma unroll
                for (int r = 0; r < 4; ++r) {
                    int m  = m0 + wid * 32 + mf * 16 + (lane >> 4) * 4 + r;
                    int bb = m >> 12;
                    int t  = m & (T_ - 1);
                    float v = (acc[mf][nf][r] + bv) * scale;
                    dst[((size_t)(bb * H_ + h) * T_ + t) * HD_ + d] = f2bf(v);
                }
        }
    } else {
        #pragma unroll
        for (int nf = 0; nf < 4; ++nf) {
            int n = n0 + nf * 16 + (lane & 15);
            float bv = bias[n];
            #pragma unroll
            for (int mf = 0; mf < 2; ++mf)
                #pragma unroll
                for (int r = 0; r < 4; ++r) {
                    int m = m0 + wid * 32 + mf * 16 + (lane >> 4) * 4 + r;
                    of[(size_t)m * E_ + n] = acc[mf][nf][r] + bv;
                }
        }
    }
}

// -------------------- Kernel 2: MFMA banded attention --------------------
// Block: 64 q-rows, 4 waves x 16 rows. Stage 160 K rows ([t0-32, t0+128)) in
// swizzled row-major LDS, V transposed to Vt[d][k] (pitch 400B, k-XOR swz).
// Wave w: S[16][96] = Q x K^T (12 MFMA), mask band, in-reg softmax,
// P -> LDS (overlay on K, after barrier), O = P x Vt (12 MFMA).
__global__ __launch_bounds__(256) void attn_kernel(
    const ushort_t* __restrict__ q, const ushort_t* __restrict__ k,
    const ushort_t* __restrict__ v, ushort_t* __restrict__ ao)
{
    __shared__ __align__(16) char smem[20480 + 25600];
    char* Ks = smem;            // [160][64] bf16, 128B rows, XOR swizzle
    char* Pb = smem;            // overlay: 4 waves x [16][104] bf16 (208B pitch)
    char* Vt = smem + 20480;    // [64][200] bf16 (400B pitch), k-XOR swizzle

    const int tid = threadIdx.x;
    const int bh  = blockIdx.y;
    const int t0  = blockIdx.x * 64;
    const int kbase = t0 - 32;
    const char* kb = (const char*)(k + (size_t)bh * T_ * HD_);
    const char* vb = (const char*)(v + (size_t)bh * T_ * HD_);
    const char* qb = (const char*)(q + (size_t)bh * T_ * HD_);

    // ---- stage: K rows + V transpose (zeros for OOB) ----
    int4 kreg[5], vreg[5];
    #pragma unroll
    for (int l = 0; l < 5; ++l) {
        int u = tid + l * 256;              // 0..1279 = 160 rows x 8 x 16B
        int row = u >> 3;
        int g = kbase + row;
        bool ok = (unsigned)g < (unsigned)T_;
        kreg[l] = ok ? *(const int4*)(kb + (size_t)g * 128 + (u & 7) * 16)
                     : make_int4(0, 0, 0, 0);
        vreg[l] = ok ? *(const int4*)(vb + (size_t)g * 128 + (u & 7) * 16)
                     : make_int4(0, 0, 0, 0);
    }
    #pragma unroll
    for (int l = 0; l < 5; ++l) {
        int u = tid + l * 256;
        int row = u >> 3;
        int cb = (u & 7) * 16;
        *(int4*)(Ks + row * 128 + (cb ^ ((row & 7) << 4))) = kreg[l];
        const u32* wv = (const u32*)&vreg[l];
        #pragma unroll
        for (int j = 0; j < 8; ++j) {
            int d = (u & 7) * 8 + j;
            ushort_t h = (j & 1) ? (ushort_t)(wv[j >> 1] >> 16)
                                 : (ushort_t)(wv[j >> 1] & 0xffffu);
            *(ushort_t*)(Vt + d * 400 + ((row * 2) ^ (((d >> 3) & 7) << 4))) = h;
        }
    }
    __syncthreads();

    const int wv_ = tid >> 6;               // wave 0..3
    const int ln  = tid & 15;
    const int lg  = (tid & 63) >> 4;        // lane group 0..3

    // Q fragments straight from global (each lane 2x16B, read exactly once)
    short8 qf[2];
    #pragma unroll
    for (int k2 = 0; k2 < 2; ++k2)
        qf[k2] = *(const short8*)(qb + (size_t)(t0 + wv_ * 16 + ln) * 128
                                  + k2 * 64 + lg * 16);

    // ---- S = Q K^T over 96-wide band ----
    f32x4 sa[6];
    #pragma unroll
    for (int nf = 0; nf < 6; ++nf) sa[nf] = (f32x4){0.f, 0.f, 0.f, 0.f};
    #pragma unroll
    for (int k2 = 0; k2 < 2; ++k2) {
        #pragma unroll
        for (int nf = 0; nf < 6; ++nf) {
            int row = wv_ * 16 + nf * 16 + ln;     // k-local row (max 143 < 160)
            short8 kf = *(const short8*)(Ks + row * 128 +
                          ((k2 * 64 + lg * 16) ^ ((row & 7) << 4)));
            sa[nf] = __builtin_amdgcn_mfma_f32_16x16x32_bf16(qf[k2], kf, sa[nf], 0, 0, 0);
        }
    }

    // ---- band mask + softmax (C-layout: m = 4*lg + r, n = 16*nf + ln) ----
    const int nm0 = ln - 4 * lg;
    #pragma unroll
    for (int nf = 0; nf < 6; ++nf)
        #pragma unroll
        for (int r = 0; r < 4; ++r) {
            int diff = nm0 + 16 * nf - r;           // n - m, window iff 0..64
            if (diff < 0 || diff > 64) sa[nf][r] = -1e30f;
        }
    float inv_[4];
    #pragma unroll
    for (int r = 0; r < 4; ++r) {
        float mx = sa[0][r];
        #pragma unroll
        for (int nf = 1; nf < 6; ++nf) mx = fmaxf(mx, sa[nf][r]);
        mx = fmaxf(mx, __shfl_xor(mx, 1));
        mx = fmaxf(mx, __shfl_xor(mx, 2));
        mx = fmaxf(mx, __shfl_xor(mx, 4));
        mx = fmaxf(mx, __shfl_xor(mx, 8));
        float s = 0.f;
        #pragma unroll
        for (int nf = 0; nf < 6; ++nf) {
            float e = __expf(sa[nf][r] - mx);
            sa[nf][r] = e;
            s += e;
        }
        s += __shfl_xor(s, 1);
        s += __shfl_xor(s, 2);
        s += __shfl_xor(s, 4);
        s += __shfl_xor(s, 8);
        inv_[r] = 1.f / s;
    }

    // ---- P -> LDS (overlay on K; barrier so all K reads are done) ----
    __syncthreads();
    char* Pw = Pb + wv_ * 3328;                     // 16 rows x 208B
    #pragma unroll
    for (int nf = 0; nf < 6; ++nf)
        #pragma unroll
        for (int r = 0; r < 4; ++r)
            *(ushort_t*)(Pw + (4 * lg + r) * 208 + (16 * nf + ln) * 2)
                = f2bf(sa[nf][r]);

    // ---- O = P x Vt ----
    f32x4 oa[4];
    #pragma unroll
    for (int nf = 0; nf < 4; ++nf) oa[nf] = (f32x4){0.f, 0.f, 0.f, 0.f};
    #pragma unroll
    for (int ks = 0; ks < 3; ++ks) {
        short8 pa = *(const short8*)(Pw + ln * 208 + ks * 64 + lg * 16);
        #pragma unroll
        for (int nf = 0; nf < 4; ++nf) {
            int d = nf * 16 + ln;
            short8 vbf = *(const short8*)(Vt + d * 400 +
                           ((32 * wv_ + 64 * ks + 16 * lg) ^ (((d >> 3) & 7) << 4)));
            oa[nf] = __builtin_amdgcn_mfma_f32_16x16x32_bf16(pa, vbf, oa[nf], 0, 0, 0);
        }
    }

    // ---- epilogue: O * inv -> aob[B][T][E] bf16 ----
    const int bb = bh >> 2, hh = bh & 3;
    #pragma unroll
    for (int nf = 0; nf < 4; ++nf)
        #pragma unroll
        for (int r = 0; r < 4; ++r) {
            int t = t0 + wv_ * 16 + 4 * lg + r;
            int d = nf * 16 + ln;
            ao[((size_t)bb * T_ + t) * E_ + hh * HD_ + d] = f2bf(oa[nf][r] * inv_[r]);
        }
}

extern "C" void kernel_launch(void* const* d_in, const int* in_sizes, int n_in,
                              void* d_out, int out_size, void* d_ws, size_t ws_size,
                              hipStream_t stream) {
    const float* x    = (const float*)d_in[0];
    const float* Wqkv = (const float*)d_in[1];
    const float* bqkv = (const float*)d_in[2];
    const float* Wout = (const float*)d_in[3];
    const float* bout = (const float*)d_in[4];
    float* out = (float*)d_out;

    char* ws = (char*)d_ws;
    ushort_t* xb  = (ushort_t*)(ws);                 // 4 MB  (8192x256)
    ushort_t* wqb = (ushort_t*)(ws + 4194304);       // 384 KB (768x256)
    ushort_t* wob = (ushort_t*)(ws + 4587520);       // 128 KB (256x256)
    ushort_t* qb  = (ushort_t*)(ws + 4718592);       // 4 MB  [BH][T][64]
    ushort_t* kbp = (ushort_t*)(ws + 8912896);       // 4 MB
    ushort_t* vbp = (ushort_t*)(ws + 13107200);      // 4 MB
    ushort_t* aob = (ushort_t*)(ws + 17301504);      // 4 MB  [B][T][256]

    cvt_kernel<<<1152, 256, 0, stream>>>(x, Wqkv, Wout, xb, wqb, wob);
    gemm_kernel<0><<<dim3(12, 64), 256, 0, stream>>>(
        (const char*)xb, (const char*)wqb, bqkv, qb, kbp, vbp, nullptr);
    attn_kernel<<<dim3(64, 8), 256, 0, stream>>>(qb, kbp, vbp, aob);
    gemm_kernel<1><<<dim3(4, 64), 256, 0, stream>>>(
        (const char*)aob, (const char*)wob, bout, nullptr, nullptr, nullptr, out);
}